// Round 8
// baseline (245.056 us; speedup 1.0000x reference)
//
#include <hip/hip_runtime.h>

// Problem constants
#define NB   2
#define ND   16
#define NH   64
#define DHW  65536       // D*H*W
#define HW   4096        // H*W
#define CDHW 16777216    // C*D*H*W

typedef __attribute__((ext_vector_type(4))) float f32x4;
typedef __attribute__((ext_vector_type(8))) short bf16x8;
typedef unsigned short ushort_t;

#define MFMA16(a, b, c) __builtin_amdgcn_mfma_f32_16x16x32_bf16((a), (b), (c), 0, 0, 0)

// ---------------- ws layout (ushort element offsets) ----------------
#define WS_WQH 0
#define WS_WQL 8192
#define WS_WKH 16384
#define WS_WKL 24576
#define WS_WVH 32768
#define WS_WVL 98304
#define WS_WEIGHT_USHORTS 163840
// A planes: [2048 groups][64 x][64 y] ushort, hi and lo
#define WS_AH  (WS_WEIGHT_USHORTS)
#define WS_AL  (WS_AH + 8388608)
#define WS_FULL_BYTES ((size_t)(WS_WEIGHT_USHORTS + 16777216) * 2)

__device__ __forceinline__ void split_val(float f, short& h, short& l) {
  unsigned int u = __builtin_bit_cast(unsigned int, f);
  h = (short)(unsigned short)(u >> 16);
  float fh = __builtin_bit_cast(float, u & 0xffff0000u);
  float r = f - fh;
  l = (short)(unsigned short)(__builtin_bit_cast(unsigned int, r) >> 16);
}

__device__ __forceinline__ void load_split8(const float* __restrict__ p, bf16x8& h8, bf16x8& l8) {
  float4 a = *(const float4*)p;
  float4 b = *(const float4*)(p + 4);
  float f[8] = {a.x, a.y, a.z, a.w, b.x, b.y, b.z, b.w};
#pragma unroll
  for (int j = 0; j < 8; ++j) {
    short hh, ll;
    split_val(f[j], hh, ll);
    h8[j] = hh; l8[j] = ll;
  }
}

// byte offset in a [rows][128 B] XOR-swizzled tile (16 B slot granularity)
__device__ __forceinline__ int swzb(int row, int colb) {
  return row * 128 + (((colb) & ~15) ^ ((row & 7) << 4)) + ((colb) & 15);
}

// ---------------- weight pre-split kernel ----------------
__global__ void prep_w(const float* __restrict__ Wq, const float* __restrict__ Wk,
                       const float* __restrict__ Wv, ushort_t* __restrict__ ws) {
  int idx = blockIdx.x * 256 + threadIdx.x;
  const float* src; int off; ushort_t *H, *L;
  if (idx < 8192)       { src = Wq; off = idx;         H = ws + WS_WQH; L = ws + WS_WQL; }
  else if (idx < 16384) { src = Wk; off = idx - 8192;  H = ws + WS_WKH; L = ws + WS_WKL; }
  else if (idx < 81920) { src = Wv; off = idx - 16384; H = ws + WS_WVH; L = ws + WS_WVL; }
  else return;
  short h, l;
  split_val(src[off], h, l);
  H[off] = (ushort_t)h;
  L[off] = (ushort_t)l;
}

// ---------------- kernel A: Q,K projection + A = Q^T K (per-wave, barrier-free) ----------------
// 512 blocks x 256 thr; wave = one (b,d,h) group. LDS 8 KB/wave chunk buffer.
__global__ __launch_bounds__(256, 2) void qk_kernel(
    const float* __restrict__ x1, const float* __restrict__ x2,
    const float* __restrict__ bq, const float* __restrict__ bk,
    ushort_t* __restrict__ ws)
{
  __shared__ char qsmem[32768];
  const int tid  = threadIdx.x;
  const int lane = tid & 63;
  const int wv   = tid >> 6;
  const int l15  = lane & 15;
  const int g    = lane >> 4;

  const int grp = blockIdx.x * 4 + wv;
  const int b   = grp >> 10;
  const int rem = grp & 1023;
  const int d   = rem >> 6;
  const int h   = rem & 63;
  const size_t base = (size_t)b * CDHW + (size_t)d * HW + (size_t)h * 64;
  const float* x1p = x1 + base;
  const float* x2p = x2 + base;

  float* buf = (float*)(qsmem + wv * 8192);   // wave-private [32 ch][64 x] f32

  const ushort_t* WqH = ws + WS_WQH;
  const ushort_t* WqL = ws + WS_WQL;
  const ushort_t* WkH = ws + WS_WKH;
  const ushort_t* WkL = ws + WS_WKL;

  // accumulators: full Q^T / K^T for the group. [c8-tile mt][x-tile nt]
  f32x4 qacc[2][4], kacc[2][4];
#pragma unroll
  for (int mt = 0; mt < 2; ++mt) {
    int r0 = mt * 16 + 4 * g;
    f32x4 bqv = (f32x4){bq[r0], bq[r0 + 1], bq[r0 + 2], bq[r0 + 3]};
    f32x4 bkv = (f32x4){bk[r0], bk[r0 + 1], bk[r0 + 2], bk[r0 + 3]};
#pragma unroll
    for (int nt = 0; nt < 4; ++nt) { qacc[mt][nt] = bqv; kacc[mt][nt] = bkv; }
  }

  const int rrow = (lane >> 4);        // 0..3 row-within-quad
  const int rcol = (lane & 15) * 4;    // x offset

  float4 rfA[8], rfB[8];
  // load chunk i (32 channels) into regs: instr k covers rows 4k..4k+3, 256B/row
  auto loadc = [&](float4* rf, int i) {
    const float* src = (i < 8 ? x1p : x2p) + (size_t)(32 * (i & 7)) * DHW;
#pragma unroll
    for (int k = 0; k < 8; ++k)
      rf[k] = *(const float4*)(src + (size_t)(4 * k + rrow) * DHW + rcol);
  };
  auto writec = [&](const float4* rf) {
#pragma unroll
    for (int k = 0; k < 8; ++k)
      *(float4*)&buf[(4 * k + rrow) * 64 + rcol] = rf[k];
  };
  // consume chunk i: build split B-frags for 4 x-tiles, 24 MFMAs into acc
  auto compute = [&](int i, f32x4 (&acc)[2][4], const ushort_t* Wh, const ushort_t* Wl) {
    const int kg0 = 32 * (i & 7) + 8 * g;
    bf16x8 bh[4], bl[4];
#pragma unroll
    for (int nt = 0; nt < 4; ++nt) {
#pragma unroll
      for (int j = 0; j < 8; ++j) {
        float f = buf[(8 * g + j) * 64 + nt * 16 + l15];
        short hh, ll;
        split_val(f, hh, ll);
        bh[nt][j] = hh; bl[nt][j] = ll;
      }
    }
#pragma unroll
    for (int mt = 0; mt < 2; ++mt) {
      bf16x8 wh = *(const bf16x8*)&Wh[(size_t)(mt * 16 + l15) * 256 + kg0];
      bf16x8 wl = *(const bf16x8*)&Wl[(size_t)(mt * 16 + l15) * 256 + kg0];
#pragma unroll
      for (int nt = 0; nt < 4; ++nt) {
        acc[mt][nt] = MFMA16(wh, bh[nt], acc[mt][nt]);
        acc[mt][nt] = MFMA16(wh, bl[nt], acc[mt][nt]);
        acc[mt][nt] = MFMA16(wl, bh[nt], acc[mt][nt]);
      }
    }
  };

  // 16 chunks (8 x1 -> Q, 8 x2 -> K), reg ping-pong, wave-private: no barriers
  loadc(rfA, 0);
#pragma unroll
  for (int i2 = 0; i2 < 8; ++i2) {
    const int i0 = 2 * i2, i1 = 2 * i2 + 1;
    loadc(rfB, i1);
    writec(rfA);
    if (i0 < 8) compute(i0, qacc, WqH, WqL); else compute(i0, kacc, WkH, WkL);
    if (i1 + 1 < 16) loadc(rfA, i1 + 1);
    writec(rfB);
    if (i1 < 8) compute(i1, qacc, WqH, WqL); else compute(i1, kacc, WkH, WkL);
  }

  // ---- A = Q^T K via in-place 8KB exchange (wave-private, in-order DS) ----
  ushort_t* ex = (ushort_t*)buf;   // [64][32] hi at 0, lo at +2048
  // Q exchange: D layout col=l15 (x-within-nt), row=mt*16+4g+r (c8)
#pragma unroll
  for (int mt = 0; mt < 2; ++mt)
#pragma unroll
    for (int nt = 0; nt < 4; ++nt)
#pragma unroll
      for (int r = 0; r < 4; ++r) {
        short hh, ll;
        split_val(qacc[mt][nt][r], hh, ll);
        int x = nt * 16 + l15;
        ex[x * 32 + mt * 16 + 4 * g + r]        = (ushort_t)hh;
        ex[2048 + x * 32 + mt * 16 + 4 * g + r] = (ushort_t)ll;
      }
  bf16x8 qh8[4], ql8[4];   // A-operand frags: row m=x=mt*16+l15, k-octet g (c8)
#pragma unroll
  for (int mt = 0; mt < 4; ++mt) {
    qh8[mt] = *(const bf16x8*)&ex[(mt * 16 + l15) * 32 + 8 * g];
    ql8[mt] = *(const bf16x8*)&ex[2048 + (mt * 16 + l15) * 32 + 8 * g];
  }
  // K exchange (overwrite same region)
#pragma unroll
  for (int mt = 0; mt < 2; ++mt)
#pragma unroll
    for (int nt = 0; nt < 4; ++nt)
#pragma unroll
      for (int r = 0; r < 4; ++r) {
        short hh, ll;
        split_val(kacc[mt][nt][r], hh, ll);
        int y = nt * 16 + l15;
        ex[y * 32 + mt * 16 + 4 * g + r]        = (ushort_t)hh;
        ex[2048 + y * 32 + mt * 16 + 4 * g + r] = (ushort_t)ll;
      }
  bf16x8 kh8[4], kl8[4];   // B-operand frags: col n=y=nt*16+l15, k-octet g (c8)
#pragma unroll
  for (int nt = 0; nt < 4; ++nt) {
    kh8[nt] = *(const bf16x8*)&ex[(nt * 16 + l15) * 32 + 8 * g];
    kl8[nt] = *(const bf16x8*)&ex[2048 + (nt * 16 + l15) * 32 + 8 * g];
  }
  // A MFMAs: K=32 exactly one mfma depth
  f32x4 aacc[4][4];
#pragma unroll
  for (int mt = 0; mt < 4; ++mt)
#pragma unroll
    for (int nt = 0; nt < 4; ++nt) {
      f32x4 a = (f32x4){0.f, 0.f, 0.f, 0.f};
      a = MFMA16(qh8[mt], kh8[nt], a);
      a = MFMA16(qh8[mt], kl8[nt], a);
      a = MFMA16(ql8[mt], kh8[nt], a);
      aacc[mt][nt] = a;
    }
  // store A split: Ah/Al [grp][x][y]
  ushort_t* Ah = ws + WS_AH + (size_t)grp * 4096;
  ushort_t* Al = ws + WS_AL + (size_t)grp * 4096;
#pragma unroll
  for (int mt = 0; mt < 4; ++mt)
#pragma unroll
    for (int nt = 0; nt < 4; ++nt)
#pragma unroll
      for (int r = 0; r < 4; ++r) {
        short hh, ll;
        split_val(aacc[mt][nt][r], hh, ll);
        int x = mt * 16 + 4 * g + r, y = nt * 16 + l15;
        Ah[x * 64 + y] = (ushort_t)hh;
        Al[x * 64 + y] = (ushort_t)ll;
      }
}

// ---------------- kernel B: V projection + Out = V A^T ----------------
// 4096 blocks = (group, channel-half). LDS 32 KB -> high occupancy.
#define B_OFF_XTH  0
#define B_OFF_XTL  8192
#define B_OFF_XLIN 16384
#define B_SMEM     32768

__global__ __launch_bounds__(256, 4) void xattn_v2(
    const float* __restrict__ x2, const float* __restrict__ bv,
    const ushort_t* __restrict__ wsp, float* __restrict__ out)
{
  __shared__ char smem[B_SMEM];
  char*  XthB = smem + B_OFF_XTH;
  char*  XtlB = smem + B_OFF_XTL;
  float* Xlin = (float*)(smem + B_OFF_XLIN);   // [64][64] f32, pad-free (0-conflict proven)

  const int tid  = threadIdx.x;
  const int lane = tid & 63;
  const int wv   = tid >> 6;
  const int l15  = lane & 15;
  const int g    = lane >> 4;

  const int bid   = blockIdx.x;
  const int grp   = bid >> 1;
  const int chalf = bid & 1;
  const int cbase = chalf * 128;
  const int b   = grp >> 10;
  const int rem = grp & 1023;
  const int d   = rem >> 6;
  const int h   = rem & 63;
  const size_t base = (size_t)b * CDHW + (size_t)d * HW + (size_t)h * 64;
  const float* x2p = x2 + base;

  const ushort_t* WvH = wsp + WS_WVH;
  const ushort_t* WvL = wsp + WS_WVL;
  const ushort_t* AhW = wsp + WS_AH + (size_t)grp * 4096;
  const ushort_t* AlW = wsp + WS_AL + (size_t)grp * 4096;

  float4 pf[4];
  auto issue_pf = [&](const float* __restrict__ src) {
#pragma unroll
    for (int i = 0; i < 4; ++i) {
      int ch = 16 * wv + g + 4 * i;
      pf[i] = *(const float4*)(src + (size_t)ch * DHW + 4 * l15);
    }
  };
  auto write_xlin = [&]() {
#pragma unroll
    for (int i = 0; i < 4; ++i) {
      int ch = 16 * wv + g + 4 * i;
      *(float4*)&Xlin[ch * 64 + 4 * l15] = pf[i];
    }
  };
  auto passB = [&]() {
#pragma unroll
    for (int bb = 0; bb < 2; ++bb) {
      int c0 = 16 * wv + 8 * bb;
      bf16x8 h8, l8;
#pragma unroll
      for (int j = 0; j < 8; ++j) {
        float f = Xlin[(c0 + j) * 64 + lane];
        short hh, ll;
        split_val(f, hh, ll);
        h8[j] = hh; l8[j] = ll;
      }
      *(bf16x8*)(XthB + swzb(lane, c0 * 2)) = h8;
      *(bf16x8*)(XtlB + swzb(lane, c0 * 2)) = l8;
    }
  };
  auto ldsx = [&](const char* B, int row, int ko) -> bf16x8 {
    return *(const bf16x8*)(B + swzb(row, ko * 2));
  };

  // V accumulators: wave's 32 channels = rows [cbase+32wv, +32)
  f32x4 vacc[2][4];
#pragma unroll
  for (int mt = 0; mt < 2; ++mt) {
    int r0 = cbase + 32 * wv + mt * 16 + 4 * g;
    f32x4 bb = (f32x4){bv[r0], bv[r0 + 1], bv[r0 + 2], bv[r0 + 3]};
#pragma unroll
    for (int nt = 0; nt < 4; ++nt) vacc[mt][nt] = bb;
  }

  issue_pf(x2p);
  write_xlin();
  __syncthreads();

  // ===== V loop: 4 c-tiles of x2 =====
  for (int t = 0; t < 4; ++t) {
    passB();
    __syncthreads();                       // Xth(t) visible; Xlin(t) free
    if (t < 3) issue_pf(x2p + (size_t)(t + 1) * 64 * DHW);
#pragma unroll
    for (int ks = 0; ks < 2; ++ks) {
      const int ko = ks * 32 + 8 * g;
      const int kg = t * 64 + ko;
      bf16x8 xh[4], xl[4];
#pragma unroll
      for (int nt = 0; nt < 4; ++nt) {
        xh[nt] = ldsx(XthB, nt * 16 + l15, ko);
        xl[nt] = ldsx(XtlB, nt * 16 + l15, ko);
      }
      __builtin_amdgcn_s_setprio(1);
#pragma unroll
      for (int mt = 0; mt < 2; ++mt) {
        bf16x8 wh = *(const bf16x8*)&WvH[(size_t)(cbase + 32 * wv + mt * 16 + l15) * 256 + kg];
        bf16x8 wl = *(const bf16x8*)&WvL[(size_t)(cbase + 32 * wv + mt * 16 + l15) * 256 + kg];
#pragma unroll
        for (int nt = 0; nt < 4; ++nt) {
          vacc[mt][nt] = MFMA16(wh, xh[nt], vacc[mt][nt]);
          vacc[mt][nt] = MFMA16(wh, xl[nt], vacc[mt][nt]);
          vacc[mt][nt] = MFMA16(wl, xh[nt], vacc[mt][nt]);
        }
      }
      __builtin_amdgcn_s_setprio(0);
    }
    if (t < 3) write_xlin();               // next tile -> Xlin
    __syncthreads();                       // Xlin(t+1) visible; Xth(t) free
  }

  // ===== PV: Out = V * A^T; Vb overlays Xlin (dead); A-frags direct from ws =====
  {
    char* VhB = smem + B_OFF_XLIN + wv * 4096;   // wave-private [16][128B] swz hi
    char* VlB = VhB + 2048;                      // lo
#pragma unroll
    for (int mt = 0; mt < 2; ++mt) {
#pragma unroll
      for (int nt = 0; nt < 4; ++nt)
#pragma unroll
        for (int r = 0; r < 4; ++r) {
          short hh, ll;
          split_val(vacc[mt][nt][r], hh, ll);
          int colb = (nt * 16 + l15) * 2;
          *(ushort_t*)(VhB + swzb(4 * g + r, colb)) = (ushort_t)hh;
          *(ushort_t*)(VlB + swzb(4 * g + r, colb)) = (ushort_t)ll;
        }
      f32x4 oacc[4];
#pragma unroll
      for (int nt = 0; nt < 4; ++nt) oacc[nt] = (f32x4){0.f, 0.f, 0.f, 0.f};
      __builtin_amdgcn_s_setprio(1);
#pragma unroll
      for (int ys = 0; ys < 2; ++ys) {
        const int yo = ys * 32 + 8 * g;
        bf16x8 vh8 = *(const bf16x8*)(VhB + swzb(l15, yo * 2));
        bf16x8 vl8 = *(const bf16x8*)(VlB + swzb(l15, yo * 2));
#pragma unroll
        for (int nt = 0; nt < 4; ++nt) {
          bf16x8 ah8 = *(const bf16x8*)&AhW[(nt * 16 + l15) * 64 + yo];
          bf16x8 al8 = *(const bf16x8*)&AlW[(nt * 16 + l15) * 64 + yo];
          oacc[nt] = MFMA16(vh8, ah8, oacc[nt]);
          oacc[nt] = MFMA16(vh8, al8, oacc[nt]);
          oacc[nt] = MFMA16(vl8, ah8, oacc[nt]);
        }
      }
      __builtin_amdgcn_s_setprio(0);
#pragma unroll
      for (int nt = 0; nt < 4; ++nt)
#pragma unroll
        for (int r = 0; r < 4; ++r)
          out[base + (size_t)(cbase + 32 * wv + mt * 16 + 4 * g + r) * DHW + nt * 16 + l15] = oacc[nt][r];
    }
  }
}

// ---------------- fused fallback (no ws): r2-structure, correctness-safe ----------------
#define XT_LD 72
#define QK_LD 40
#define A_LD  72
#define VB_LD 72
#define F_OFF_XTH 0
#define F_OFF_XTL 9216
#define F_OFF_R2  18432
#define F_OFF_KH  18432
#define F_OFF_KL  23552
#define F_OFF_AH  0
#define F_OFF_AL  9216
#define F_OFF_QH  36864
#define F_OFF_QL  41984
#define F_SMEM 47104

__global__ __launch_bounds__(256, 3) void xattn_fallback(
    const float* __restrict__ x1, const float* __restrict__ x2,
    const float* __restrict__ Wq, const float* __restrict__ bq,
    const float* __restrict__ Wk, const float* __restrict__ bk,
    const float* __restrict__ Wv, const float* __restrict__ bv,
    float* __restrict__ out)
{
  __shared__ char smem[F_SMEM];
  ushort_t* Xth  = (ushort_t*)(smem + F_OFF_XTH);
  ushort_t* Xtl  = (ushort_t*)(smem + F_OFF_XTL);
  float*    Xlin = (float*)(smem + F_OFF_R2);
  ushort_t* Kh   = (ushort_t*)(smem + F_OFF_KH);
  ushort_t* Kl   = (ushort_t*)(smem + F_OFF_KL);
  ushort_t* Vb   = (ushort_t*)(smem + F_OFF_R2);
  ushort_t* Ah   = (ushort_t*)(smem + F_OFF_AH);
  ushort_t* Al   = (ushort_t*)(smem + F_OFF_AL);
  ushort_t* Qh   = (ushort_t*)(smem + F_OFF_QH);
  ushort_t* Ql   = (ushort_t*)(smem + F_OFF_QL);

  const int tid  = threadIdx.x;
  const int lane = tid & 63;
  const int wv   = tid >> 6;
  const int l15  = lane & 15;
  const int g    = lane >> 4;

  const int grp = blockIdx.x;
  const int b   = grp >> 10;
  const int rem = grp & 1023;
  const int d   = rem >> 6;
  const int h   = rem & 63;
  const size_t base = (size_t)b * CDHW + (size_t)d * HW + (size_t)h * 64;

  auto passA = [&](const float* __restrict__ src) {
#pragma unroll
    for (int i = 0; i < 4; ++i) {
      int ch = 16 * wv + (lane >> 4) + 4 * i;
      int c4 = (lane & 15) << 2;
      float4 v = *(const float4*)(src + (size_t)ch * DHW + c4);
      *(float4*)&Xlin[ch * 66 + c4] = v;
    }
  };
  auto passB = [&]() {
#pragma unroll
    for (int bb = 0; bb < 2; ++bb) {
      int c0 = 16 * wv + 8 * bb;
      bf16x8 h8, l8;
#pragma unroll
      for (int j = 0; j < 8; ++j) {
        float f = Xlin[(c0 + j) * 66 + lane];
        short hh, ll;
        split_val(f, hh, ll);
        h8[j] = hh; l8[j] = ll;
      }
      *(bf16x8*)&Xth[lane * XT_LD + c0] = h8;
      *(bf16x8*)&Xtl[lane * XT_LD + c0] = l8;
    }
  };

  {
    f32x4 qacc[2];
#pragma unroll
    for (int mt = 0; mt < 2; ++mt) {
      int r0 = mt * 16 + 4 * g;
      qacc[mt] = (f32x4){bq[r0], bq[r0 + 1], bq[r0 + 2], bq[r0 + 3]};
    }
    const float* x1p = x1 + base;
    for (int t = 0; t < 4; ++t) {
      passA(x1p + (size_t)t * 64 * DHW);
      __syncthreads();
      passB();
      __syncthreads();
#pragma unroll
      for (int ks = 0; ks < 2; ++ks) {
        const int ko = ks * 32 + 8 * g;
        const int kg = t * 64 + ko;
        bf16x8 bh = *(const bf16x8*)&Xth[(16 * wv + l15) * XT_LD + ko];
        bf16x8 bl = *(const bf16x8*)&Xtl[(16 * wv + l15) * XT_LD + ko];
#pragma unroll
        for (int mt = 0; mt < 2; ++mt) {
          bf16x8 wh, wl;
          load_split8(Wq + (size_t)(mt * 16 + l15) * 256 + kg, wh, wl);
          qacc[mt] = MFMA16(wh, bh, qacc[mt]);
          qacc[mt] = MFMA16(wh, bl, qacc[mt]);
          qacc[mt] = MFMA16(wl, bh, qacc[mt]);
        }
      }
      __syncthreads();
    }
    const int x = 16 * wv + l15;
#pragma unroll
    for (int mt = 0; mt < 2; ++mt)
#pragma unroll
      for (int r = 0; r < 4; ++r) {
        short hh, ll;
        split_val(qacc[mt][r], hh, ll);
        Qh[x * QK_LD + mt * 16 + 4 * g + r] = (ushort_t)hh;
        Ql[x * QK_LD + mt * 16 + 4 * g + r] = (ushort_t)ll;
      }
  }

  f32x4 vacc[4][4];
  {
    f32x4 kacc[2];
#pragma unroll
    for (int mt = 0; mt < 2; ++mt) {
      int r0 = mt * 16 + 4 * g;
      kacc[mt] = (f32x4){bk[r0], bk[r0 + 1], bk[r0 + 2], bk[r0 + 3]};
    }
#pragma unroll
    for (int mt = 0; mt < 4; ++mt) {
      int r0 = 64 * wv + mt * 16 + 4 * g;
      f32x4 bb = (f32x4){bv[r0], bv[r0 + 1], bv[r0 + 2], bv[r0 + 3]};
#pragma unroll
      for (int nt = 0; nt < 4; ++nt) vacc[mt][nt] = bb;
    }
    const float* x2p = x2 + base;
    for (int t = 0; t < 4; ++t) {
      passA(x2p + (size_t)t * 64 * DHW);
      __syncthreads();
      passB();
      __syncthreads();
#pragma unroll
      for (int ks = 0; ks < 2; ++ks) {
        const int ko = ks * 32 + 8 * g;
        const int kg = t * 64 + ko;
        bf16x8 xh[4], xl[4];
#pragma unroll
        for (int nt = 0; nt < 4; ++nt) {
          xh[nt] = *(const bf16x8*)&Xth[(nt * 16 + l15) * XT_LD + ko];
          xl[nt] = *(const bf16x8*)&Xtl[(nt * 16 + l15) * XT_LD + ko];
        }
        {
          bf16x8 bh = *(const bf16x8*)&Xth[(16 * wv + l15) * XT_LD + ko];
          bf16x8 bl = *(const bf16x8*)&Xtl[(16 * wv + l15) * XT_LD + ko];
#pragma unroll
          for (int mt = 0; mt < 2; ++mt) {
            bf16x8 wh, wl;
            load_split8(Wk + (size_t)(mt * 16 + l15) * 256 + kg, wh, wl);
            kacc[mt] = MFMA16(wh, bh, kacc[mt]);
            kacc[mt] = MFMA16(wh, bl, kacc[mt]);
            kacc[mt] = MFMA16(wl, bh, kacc[mt]);
          }
        }
#pragma unroll
        for (int mt = 0; mt < 4; ++mt) {
          bf16x8 wh, wl;
          load_split8(Wv + (size_t)(64 * wv + mt * 16 + l15) * 256 + kg, wh, wl);
#pragma unroll
          for (int nt = 0; nt < 4; ++nt) {
            vacc[mt][nt] = MFMA16(wh, xh[nt], vacc[mt][nt]);
            vacc[mt][nt] = MFMA16(wh, xl[nt], vacc[mt][nt]);
            vacc[mt][nt] = MFMA16(wl, xh[nt], vacc[mt][nt]);
          }
        }
      }
      __syncthreads();
    }
    const int y = 16 * wv + l15;
#pragma unroll
    for (int mt = 0; mt < 2; ++mt)
#pragma unroll
      for (int r = 0; r < 4; ++r) {
        short hh, ll;
        split_val(kacc[mt][r], hh, ll);
        Kh[y * QK_LD + mt * 16 + 4 * g + r] = (ushort_t)hh;
        Kl[y * QK_LD + mt * 16 + 4 * g + r] = (ushort_t)ll;
      }
  }
  __syncthreads();

  {
    const int y = 16 * wv + l15;
    bf16x8 kh = *(const bf16x8*)&Kh[y * QK_LD + 8 * g];
    bf16x8 kl = *(const bf16x8*)&Kl[y * QK_LD + 8 * g];
    f32x4 acc[4];
#pragma unroll
    for (int mt = 0; mt < 4; ++mt) acc[mt] = (f32x4){0.f, 0.f, 0.f, 0.f};
#pragma unroll
    for (int mt = 0; mt < 4; ++mt) {
      bf16x8 qh = *(const bf16x8*)&Qh[(mt * 16 + l15) * QK_LD + 8 * g];
      bf16x8 ql = *(const bf16x8*)&Ql[(mt * 16 + l15) * QK_LD + 8 * g];
      acc[mt] = MFMA16(qh, kh, acc[mt]);
      acc[mt] = MFMA16(qh, kl, acc[mt]);
      acc[mt] = MFMA16(ql, kh, acc[mt]);
    }
#pragma unroll
    for (int mt = 0; mt < 4; ++mt)
#pragma unroll
      for (int r = 0; r < 4; ++r) {
        short hh, ll;
        split_val(acc[mt][r], hh, ll);
        Ah[(mt * 16 + 4 * g + r) * A_LD + y] = (ushort_t)hh;
        Al[(mt * 16 + 4 * g + r) * A_LD + y] = (ushort_t)ll;
      }
  }
  __syncthreads();

  {
    ushort_t* Vh = Vb + wv * 2304;
    ushort_t* Vl = Vh + 1152;
    const int cb = 64 * wv;
#pragma unroll
    for (int mt = 0; mt < 4; ++mt) {
#pragma unroll
      for (int nt = 0; nt < 4; ++nt)
#pragma unroll
        for (int r = 0; r < 4; ++r) {
          short hh, ll;
          split_val(vacc[mt][nt][r], hh, ll);
          Vh[(4 * g + r) * VB_LD + nt * 16 + l15] = (ushort_t)hh;
          Vl[(4 * g + r) * VB_LD + nt * 16 + l15] = (ushort_t)ll;
        }
      f32x4 oacc[4];
#pragma unroll
      for (int nt = 0; nt < 4; ++nt) oacc[nt] = (f32x4){0.f, 0.f, 0.f, 0.f};
#pragma unroll
      for (int ys = 0; ys < 2; ++ys) {
        const int yo = ys * 32 + 8 * g;
        bf16x8 vh8 = *(const bf16x8*)&Vh[l15 * VB_LD + yo];
        bf16x8 vl8 = *(const bf16x8*)&Vl[l15 * VB_LD + yo];
#pragma unroll
        for (int nt = 0; nt < 4; ++nt) {
          bf16x8 ah8 = *(const bf16x8*)&Ah[(nt * 16 + l15) * A_LD + yo];
          bf16x8 al8 = *(const bf16x8*)&Al[(nt * 16 + l15) * A_LD + yo];
          oacc[nt] = MFMA16(vh8, ah8, oacc[nt]);
          oacc[nt] = MFMA16(vh8, al8, oacc[nt]);
          oacc[nt] = MFMA16(vl8, ah8, oacc[nt]);
        }
      }
#pragma unroll
      for (int nt = 0; nt < 4; ++nt)
#pragma unroll
        for (int r = 0; r < 4; ++r)
          out[base + (size_t)(cb + mt * 16 + 4 * g + r) * DHW + nt * 16 + l15] = oacc[nt][r];
    }
  }
}

extern "C" void kernel_launch(void* const* d_in, const int* in_sizes, int n_in,
                              void* d_out, int out_size, void* d_ws, size_t ws_size,
                              hipStream_t stream)
{
  const float* x1 = (const float*)d_in[0];
  const float* x2 = (const float*)d_in[1];
  const float* Wq = (const float*)d_in[2];
  const float* bq = (const float*)d_in[3];
  const float* Wk = (const float*)d_in[4];
  const float* bk = (const float*)d_in[5];
  const float* Wv = (const float*)d_in[6];
  const float* bv = (const float*)d_in[7];
  float* out = (float*)d_out;

  if (d_ws && ws_size >= WS_FULL_BYTES) {
    ushort_t* ws = (ushort_t*)d_ws;
    hipLaunchKernelGGL(prep_w, dim3(320), dim3(256), 0, stream, Wq, Wk, Wv, ws);
    hipLaunchKernelGGL(qk_kernel, dim3(512), dim3(256), 0, stream, x1, x2, bq, bk, ws);
    hipLaunchKernelGGL(xattn_v2, dim3(4096), dim3(256), 0, stream, x2, bv, ws, out);
  } else {
    hipLaunchKernelGGL(xattn_fallback, dim3(NB * ND * NH), dim3(256), 0, stream,
                       x1, x2, Wq, bq, Wk, bk, Wv, bv, out);
  }
}

// Round 9
// 214.445 us; speedup vs baseline: 1.1427x; 1.1427x over previous
//
#include <hip/hip_runtime.h>

// Problem constants
#define NB   2
#define ND   16
#define NH   64
#define DHW  65536       // D*H*W
#define HW   4096        // H*W
#define CDHW 16777216    // C*D*H*W

typedef __attribute__((ext_vector_type(4))) float f32x4;
typedef __attribute__((ext_vector_type(8))) short bf16x8;
typedef unsigned short ushort_t;

#define MFMA16(a, b, c) __builtin_amdgcn_mfma_f32_16x16x32_bf16((a), (b), (c), 0, 0, 0)

// ---------------- ws layout (ushort element offsets) ----------------
#define WS_WQH 0
#define WS_WQL 8192
#define WS_WKH 16384
#define WS_WKL 24576
#define WS_WVH 32768
#define WS_WVL 98304
#define WS_WEIGHT_USHORTS 163840
// A planes: [2048 groups][64 x][64 y] ushort, hi and lo
#define WS_AH  (WS_WEIGHT_USHORTS)
#define WS_AL  (WS_AH + 8388608)
#define WS_FULL_BYTES ((size_t)(WS_WEIGHT_USHORTS + 16777216) * 2)

__device__ __forceinline__ void split_val(float f, short& h, short& l) {
  unsigned int u = __builtin_bit_cast(unsigned int, f);
  h = (short)(unsigned short)(u >> 16);
  float fh = __builtin_bit_cast(float, u & 0xffff0000u);
  float r = f - fh;
  l = (short)(unsigned short)(__builtin_bit_cast(unsigned int, r) >> 16);
}

__device__ __forceinline__ void load_split8(const float* __restrict__ p, bf16x8& h8, bf16x8& l8) {
  float4 a = *(const float4*)p;
  float4 b = *(const float4*)(p + 4);
  float f[8] = {a.x, a.y, a.z, a.w, b.x, b.y, b.z, b.w};
#pragma unroll
  for (int j = 0; j < 8; ++j) {
    short hh, ll;
    split_val(f[j], hh, ll);
    h8[j] = hh; l8[j] = ll;
  }
}

// byte offset in a [rows][128 B] XOR-swizzled tile (16 B slot granularity)
__device__ __forceinline__ int swzb(int row, int colb) {
  return row * 128 + (((colb) & ~15) ^ ((row & 7) << 4)) + ((colb) & 15);
}

// ---------------- weight pre-split kernel ----------------
__global__ void prep_w(const float* __restrict__ Wq, const float* __restrict__ Wk,
                       const float* __restrict__ Wv, ushort_t* __restrict__ ws) {
  int idx = blockIdx.x * 256 + threadIdx.x;
  const float* src; int off; ushort_t *H, *L;
  if (idx < 8192)       { src = Wq; off = idx;         H = ws + WS_WQH; L = ws + WS_WQL; }
  else if (idx < 16384) { src = Wk; off = idx - 8192;  H = ws + WS_WKH; L = ws + WS_WKL; }
  else if (idx < 81920) { src = Wv; off = idx - 16384; H = ws + WS_WVH; L = ws + WS_WVL; }
  else return;
  short h, l;
  split_val(src[off], h, l);
  H[off] = (ushort_t)h;
  L[off] = (ushort_t)l;
}

// ---------------- kernel A: Q,K projection + A = Q^T K (per-wave, barrier-free) ----------------
__global__ __launch_bounds__(256, 2) void qk_kernel(
    const float* __restrict__ x1, const float* __restrict__ x2,
    const float* __restrict__ bq, const float* __restrict__ bk,
    ushort_t* __restrict__ ws)
{
  __shared__ char qsmem[32768];
  const int tid  = threadIdx.x;
  const int lane = tid & 63;
  const int wv   = tid >> 6;
  const int l15  = lane & 15;
  const int g    = lane >> 4;

  const int grp = blockIdx.x * 4 + wv;
  const int b   = grp >> 10;
  const int rem = grp & 1023;
  const int d   = rem >> 6;
  const int h   = rem & 63;
  const size_t base = (size_t)b * CDHW + (size_t)d * HW + (size_t)h * 64;
  const float* x1p = x1 + base;
  const float* x2p = x2 + base;

  float* buf = (float*)(qsmem + wv * 8192);   // wave-private [32 ch][64 x] f32

  const ushort_t* WqH = ws + WS_WQH;
  const ushort_t* WqL = ws + WS_WQL;
  const ushort_t* WkH = ws + WS_WKH;
  const ushort_t* WkL = ws + WS_WKL;

  f32x4 qacc[2][4], kacc[2][4];
#pragma unroll
  for (int mt = 0; mt < 2; ++mt) {
    int r0 = mt * 16 + 4 * g;
    f32x4 bqv = (f32x4){bq[r0], bq[r0 + 1], bq[r0 + 2], bq[r0 + 3]};
    f32x4 bkv = (f32x4){bk[r0], bk[r0 + 1], bk[r0 + 2], bk[r0 + 3]};
#pragma unroll
    for (int nt = 0; nt < 4; ++nt) { qacc[mt][nt] = bqv; kacc[mt][nt] = bkv; }
  }

  const int rrow = (lane >> 4);
  const int rcol = (lane & 15) * 4;

  float4 rfA[8], rfB[8];
  auto loadc = [&](float4* rf, int i) {
    const float* src = (i < 8 ? x1p : x2p) + (size_t)(32 * (i & 7)) * DHW;
#pragma unroll
    for (int k = 0; k < 8; ++k)
      rf[k] = *(const float4*)(src + (size_t)(4 * k + rrow) * DHW + rcol);
  };
  auto writec = [&](const float4* rf) {
#pragma unroll
    for (int k = 0; k < 8; ++k)
      *(float4*)&buf[(4 * k + rrow) * 64 + rcol] = rf[k];
  };
  auto compute = [&](int i, f32x4 (&acc)[2][4], const ushort_t* Wh, const ushort_t* Wl) {
    const int kg0 = 32 * (i & 7) + 8 * g;
    // batch weight frags first (one drain, off the per-mt path)
    bf16x8 wh0 = *(const bf16x8*)&Wh[(size_t)(l15) * 256 + kg0];
    bf16x8 wl0 = *(const bf16x8*)&Wl[(size_t)(l15) * 256 + kg0];
    bf16x8 wh1 = *(const bf16x8*)&Wh[(size_t)(16 + l15) * 256 + kg0];
    bf16x8 wl1 = *(const bf16x8*)&Wl[(size_t)(16 + l15) * 256 + kg0];
    bf16x8 bh[4], bl[4];
#pragma unroll
    for (int nt = 0; nt < 4; ++nt) {
#pragma unroll
      for (int j = 0; j < 8; ++j) {
        float f = buf[(8 * g + j) * 64 + nt * 16 + l15];
        short hh, ll;
        split_val(f, hh, ll);
        bh[nt][j] = hh; bl[nt][j] = ll;
      }
    }
#pragma unroll
    for (int nt = 0; nt < 4; ++nt) {
      acc[0][nt] = MFMA16(wh0, bh[nt], acc[0][nt]);
      acc[0][nt] = MFMA16(wh0, bl[nt], acc[0][nt]);
      acc[0][nt] = MFMA16(wl0, bh[nt], acc[0][nt]);
      acc[1][nt] = MFMA16(wh1, bh[nt], acc[1][nt]);
      acc[1][nt] = MFMA16(wh1, bl[nt], acc[1][nt]);
      acc[1][nt] = MFMA16(wl1, bh[nt], acc[1][nt]);
    }
  };

  loadc(rfA, 0);
#pragma unroll
  for (int i2 = 0; i2 < 8; ++i2) {
    const int i0 = 2 * i2, i1 = 2 * i2 + 1;
    loadc(rfB, i1);
    writec(rfA);
    if (i0 < 8) compute(i0, qacc, WqH, WqL); else compute(i0, kacc, WkH, WkL);
    if (i1 + 1 < 16) loadc(rfA, i1 + 1);
    writec(rfB);
    if (i1 < 8) compute(i1, qacc, WqH, WqL); else compute(i1, kacc, WkH, WkL);
  }

  // ---- A = Q^T K via in-place 8KB exchange (wave-private, in-order DS) ----
  ushort_t* ex = (ushort_t*)buf;
#pragma unroll
  for (int mt = 0; mt < 2; ++mt)
#pragma unroll
    for (int nt = 0; nt < 4; ++nt)
#pragma unroll
      for (int r = 0; r < 4; ++r) {
        short hh, ll;
        split_val(qacc[mt][nt][r], hh, ll);
        int x = nt * 16 + l15;
        ex[x * 32 + mt * 16 + 4 * g + r]        = (ushort_t)hh;
        ex[2048 + x * 32 + mt * 16 + 4 * g + r] = (ushort_t)ll;
      }
  bf16x8 qh8[4], ql8[4];
#pragma unroll
  for (int mt = 0; mt < 4; ++mt) {
    qh8[mt] = *(const bf16x8*)&ex[(mt * 16 + l15) * 32 + 8 * g];
    ql8[mt] = *(const bf16x8*)&ex[2048 + (mt * 16 + l15) * 32 + 8 * g];
  }
#pragma unroll
  for (int mt = 0; mt < 2; ++mt)
#pragma unroll
    for (int nt = 0; nt < 4; ++nt)
#pragma unroll
      for (int r = 0; r < 4; ++r) {
        short hh, ll;
        split_val(kacc[mt][nt][r], hh, ll);
        int y = nt * 16 + l15;
        ex[y * 32 + mt * 16 + 4 * g + r]        = (ushort_t)hh;
        ex[2048 + y * 32 + mt * 16 + 4 * g + r] = (ushort_t)ll;
      }
  bf16x8 kh8[4], kl8[4];
#pragma unroll
  for (int nt = 0; nt < 4; ++nt) {
    kh8[nt] = *(const bf16x8*)&ex[(nt * 16 + l15) * 32 + 8 * g];
    kl8[nt] = *(const bf16x8*)&ex[2048 + (nt * 16 + l15) * 32 + 8 * g];
  }
  f32x4 aacc[4][4];
#pragma unroll
  for (int mt = 0; mt < 4; ++mt)
#pragma unroll
    for (int nt = 0; nt < 4; ++nt) {
      f32x4 a = (f32x4){0.f, 0.f, 0.f, 0.f};
      a = MFMA16(qh8[mt], kh8[nt], a);
      a = MFMA16(qh8[mt], kl8[nt], a);
      a = MFMA16(ql8[mt], kh8[nt], a);
      aacc[mt][nt] = a;
    }
  ushort_t* Ah = ws + WS_AH + (size_t)grp * 4096;
  ushort_t* Al = ws + WS_AL + (size_t)grp * 4096;
#pragma unroll
  for (int mt = 0; mt < 4; ++mt)
#pragma unroll
    for (int nt = 0; nt < 4; ++nt)
#pragma unroll
      for (int r = 0; r < 4; ++r) {
        short hh, ll;
        split_val(aacc[mt][nt][r], hh, ll);
        int x = mt * 16 + 4 * g + r, y = nt * 16 + l15;
        Ah[x * 64 + y] = (ushort_t)hh;
        Al[x * 64 + y] = (ushort_t)ll;
      }
}

// ---------------- kernel B: V projection + Out = V A^T (weights batched, A in LDS) ----------------
// 4096 blocks = (group, channel-half). LDS 48 KB -> 3 blocks/CU.
#define B_OFF_XTH  0
#define B_OFF_XTL  8192
#define B_OFF_AH   16384
#define B_OFF_AL   24576
#define B_OFF_XLIN 32768
#define B_SMEM     49152

__global__ __launch_bounds__(256, 3) void xattn_v3(
    const float* __restrict__ x2, const float* __restrict__ bv,
    const ushort_t* __restrict__ wsp, float* __restrict__ out)
{
  __shared__ char smem[B_SMEM];
  char*  XthB = smem + B_OFF_XTH;
  char*  XtlB = smem + B_OFF_XTL;
  char*  AhL  = smem + B_OFF_AH;               // [64][128B] swz
  char*  AlL  = smem + B_OFF_AL;
  float* Xlin = (float*)(smem + B_OFF_XLIN);   // [64][64] f32 -> Vb overlay in PV

  const int tid  = threadIdx.x;
  const int lane = tid & 63;
  const int wv   = tid >> 6;
  const int l15  = lane & 15;
  const int g    = lane >> 4;

  const int bid   = blockIdx.x;
  const int grp   = bid >> 1;
  const int chalf = bid & 1;
  const int cbase = chalf * 128;
  const int b   = grp >> 10;
  const int rem = grp & 1023;
  const int d   = rem >> 6;
  const int h   = rem & 63;
  const size_t base = (size_t)b * CDHW + (size_t)d * HW + (size_t)h * 64;
  const float* x2p = x2 + base;

  const ushort_t* WvH = wsp + WS_WVH;
  const ushort_t* WvL = wsp + WS_WVL;
  const ushort_t* AhW = wsp + WS_AH + (size_t)grp * 4096;
  const ushort_t* AlW = wsp + WS_AL + (size_t)grp * 4096;

  float4 pf[4];
  auto issue_pf = [&](const float* __restrict__ src) {
#pragma unroll
    for (int i = 0; i < 4; ++i) {
      int ch = 16 * wv + g + 4 * i;
      pf[i] = *(const float4*)(src + (size_t)ch * DHW + 4 * l15);
    }
  };
  auto write_xlin = [&]() {
#pragma unroll
    for (int i = 0; i < 4; ++i) {
      int ch = 16 * wv + g + 4 * i;
      *(float4*)&Xlin[ch * 64 + 4 * l15] = pf[i];
    }
  };
  auto passB = [&]() {
#pragma unroll
    for (int bb = 0; bb < 2; ++bb) {
      int c0 = 16 * wv + 8 * bb;
      bf16x8 h8, l8;
#pragma unroll
      for (int j = 0; j < 8; ++j) {
        float f = Xlin[(c0 + j) * 64 + lane];
        short hh, ll;
        split_val(f, hh, ll);
        h8[j] = hh; l8[j] = ll;
      }
      *(bf16x8*)(XthB + swzb(lane, c0 * 2)) = h8;
      *(bf16x8*)(XtlB + swzb(lane, c0 * 2)) = l8;
    }
  };
  auto ldsx = [&](const char* B, int row, int ko) -> bf16x8 {
    return *(const bf16x8*)(B + swzb(row, ko * 2));
  };

  // V accumulators: wave's 32 channels
  f32x4 vacc[2][4];
#pragma unroll
  for (int mt = 0; mt < 2; ++mt) {
    int r0 = cbase + 32 * wv + mt * 16 + 4 * g;
    f32x4 bb = (f32x4){bv[r0], bv[r0 + 1], bv[r0 + 2], bv[r0 + 3]};
#pragma unroll
    for (int nt = 0; nt < 4; ++nt) vacc[mt][nt] = bb;
  }

  // ===== prologue: tile0 prefetch + cooperative A -> swizzled LDS =====
  issue_pf(x2p);
  {
#pragma unroll
    for (int rr = 0; rr < 2; ++rr) {
      int idx = tid + rr * 256;              // 0..511 per plane
      int row = idx >> 3;
      int seg = idx & 7;
      bf16x8 vh = *(const bf16x8*)&AhW[row * 64 + seg * 8];
      bf16x8 vl = *(const bf16x8*)&AlW[row * 64 + seg * 8];
      *(bf16x8*)(AhL + swzb(row, seg * 16)) = vh;
      *(bf16x8*)(AlL + swzb(row, seg * 16)) = vl;
    }
  }
  write_xlin();
  __syncthreads();

  // ===== V loop: 4 c-tiles of x2; weight frags batched per tile =====
  for (int t = 0; t < 4; ++t) {
    // issue this tile's 8 weight frags early: latency hides under passB + barrier
    bf16x8 w_h[2][2], w_l[2][2];             // [ks][mt], static indices only
#pragma unroll
    for (int ks = 0; ks < 2; ++ks) {
      const int kg = t * 64 + ks * 32 + 8 * g;
#pragma unroll
      for (int mt = 0; mt < 2; ++mt) {
        w_h[ks][mt] = *(const bf16x8*)&WvH[(size_t)(cbase + 32 * wv + mt * 16 + l15) * 256 + kg];
        w_l[ks][mt] = *(const bf16x8*)&WvL[(size_t)(cbase + 32 * wv + mt * 16 + l15) * 256 + kg];
      }
    }
    passB();
    __syncthreads();                         // Xth(t) visible; Xlin free
    if (t < 3) issue_pf(x2p + (size_t)(t + 1) * 64 * DHW);
#pragma unroll
    for (int ks = 0; ks < 2; ++ks) {
      const int ko = ks * 32 + 8 * g;
      bf16x8 xh[4], xl[4];
#pragma unroll
      for (int nt = 0; nt < 4; ++nt) {
        xh[nt] = ldsx(XthB, nt * 16 + l15, ko);
        xl[nt] = ldsx(XtlB, nt * 16 + l15, ko);
      }
      __builtin_amdgcn_s_setprio(1);
#pragma unroll
      for (int mt = 0; mt < 2; ++mt) {
#pragma unroll
        for (int nt = 0; nt < 4; ++nt) {
          vacc[mt][nt] = MFMA16(w_h[ks][mt], xh[nt], vacc[mt][nt]);
          vacc[mt][nt] = MFMA16(w_h[ks][mt], xl[nt], vacc[mt][nt]);
          vacc[mt][nt] = MFMA16(w_l[ks][mt], xh[nt], vacc[mt][nt]);
        }
      }
      __builtin_amdgcn_s_setprio(0);
    }
    if (t < 3) write_xlin();
    __syncthreads();                         // Xlin(t+1) visible; Xth(t) free
  }

  // ===== PV: Out = V * A^T; Vb overlays Xlin; A from LDS =====
  {
    char* VhB = smem + B_OFF_XLIN + wv * 4096;
    char* VlB = VhB + 2048;
#pragma unroll
    for (int mt = 0; mt < 2; ++mt) {
#pragma unroll
      for (int nt = 0; nt < 4; ++nt)
#pragma unroll
        for (int r = 0; r < 4; ++r) {
          short hh, ll;
          split_val(vacc[mt][nt][r], hh, ll);
          int colb = (nt * 16 + l15) * 2;
          *(ushort_t*)(VhB + swzb(4 * g + r, colb)) = (ushort_t)hh;
          *(ushort_t*)(VlB + swzb(4 * g + r, colb)) = (ushort_t)ll;
        }
      f32x4 oacc[4];
#pragma unroll
      for (int nt = 0; nt < 4; ++nt) oacc[nt] = (f32x4){0.f, 0.f, 0.f, 0.f};
      __builtin_amdgcn_s_setprio(1);
#pragma unroll
      for (int ys = 0; ys < 2; ++ys) {
        const int yo = ys * 32 + 8 * g;
        bf16x8 vh8 = *(const bf16x8*)(VhB + swzb(l15, yo * 2));
        bf16x8 vl8 = *(const bf16x8*)(VlB + swzb(l15, yo * 2));
#pragma unroll
        for (int nt = 0; nt < 4; ++nt) {
          bf16x8 ah8 = ldsx(AhL, nt * 16 + l15, yo);
          bf16x8 al8 = ldsx(AlL, nt * 16 + l15, yo);
          oacc[nt] = MFMA16(vh8, ah8, oacc[nt]);
          oacc[nt] = MFMA16(vh8, al8, oacc[nt]);
          oacc[nt] = MFMA16(vl8, ah8, oacc[nt]);
        }
      }
      __builtin_amdgcn_s_setprio(0);
#pragma unroll
      for (int nt = 0; nt < 4; ++nt)
#pragma unroll
        for (int r = 0; r < 4; ++r)
          out[base + (size_t)(cbase + 32 * wv + mt * 16 + 4 * g + r) * DHW + nt * 16 + l15] = oacc[nt][r];
    }
  }
}

// ---------------- fused fallback (no ws) ----------------
#define XT_LD 72
#define QK_LD 40
#define A_LD  72
#define VB_LD 72
#define F_OFF_XTH 0
#define F_OFF_XTL 9216
#define F_OFF_R2  18432
#define F_OFF_KH  18432
#define F_OFF_KL  23552
#define F_OFF_AH  0
#define F_OFF_AL  9216
#define F_OFF_QH  36864
#define F_OFF_QL  41984
#define F_SMEM 47104

__global__ __launch_bounds__(256, 3) void xattn_fallback(
    const float* __restrict__ x1, const float* __restrict__ x2,
    const float* __restrict__ Wq, const float* __restrict__ bq,
    const float* __restrict__ Wk, const float* __restrict__ bk,
    const float* __restrict__ Wv, const float* __restrict__ bv,
    float* __restrict__ out)
{
  __shared__ char smem[F_SMEM];
  ushort_t* Xth  = (ushort_t*)(smem + F_OFF_XTH);
  ushort_t* Xtl  = (ushort_t*)(smem + F_OFF_XTL);
  float*    Xlin = (float*)(smem + F_OFF_R2);
  ushort_t* Kh   = (ushort_t*)(smem + F_OFF_KH);
  ushort_t* Kl   = (ushort_t*)(smem + F_OFF_KL);
  ushort_t* Vb   = (ushort_t*)(smem + F_OFF_R2);
  ushort_t* Ah   = (ushort_t*)(smem + F_OFF_AH);
  ushort_t* Al   = (ushort_t*)(smem + F_OFF_AL);
  ushort_t* Qh   = (ushort_t*)(smem + F_OFF_QH);
  ushort_t* Ql   = (ushort_t*)(smem + F_OFF_QL);

  const int tid  = threadIdx.x;
  const int lane = tid & 63;
  const int wv   = tid >> 6;
  const int l15  = lane & 15;
  const int g    = lane >> 4;

  const int grp = blockIdx.x;
  const int b   = grp >> 10;
  const int rem = grp & 1023;
  const int d   = rem >> 6;
  const int h   = rem & 63;
  const size_t base = (size_t)b * CDHW + (size_t)d * HW + (size_t)h * 64;

  auto passA = [&](const float* __restrict__ src) {
#pragma unroll
    for (int i = 0; i < 4; ++i) {
      int ch = 16 * wv + (lane >> 4) + 4 * i;
      int c4 = (lane & 15) << 2;
      float4 v = *(const float4*)(src + (size_t)ch * DHW + c4);
      *(float4*)&Xlin[ch * 66 + c4] = v;
    }
  };
  auto passB = [&]() {
#pragma unroll
    for (int bb = 0; bb < 2; ++bb) {
      int c0 = 16 * wv + 8 * bb;
      bf16x8 h8, l8;
#pragma unroll
      for (int j = 0; j < 8; ++j) {
        float f = Xlin[(c0 + j) * 66 + lane];
        short hh, ll;
        split_val(f, hh, ll);
        h8[j] = hh; l8[j] = ll;
      }
      *(bf16x8*)&Xth[lane * XT_LD + c0] = h8;
      *(bf16x8*)&Xtl[lane * XT_LD + c0] = l8;
    }
  };

  {
    f32x4 qacc[2];
#pragma unroll
    for (int mt = 0; mt < 2; ++mt) {
      int r0 = mt * 16 + 4 * g;
      qacc[mt] = (f32x4){bq[r0], bq[r0 + 1], bq[r0 + 2], bq[r0 + 3]};
    }
    const float* x1p = x1 + base;
    for (int t = 0; t < 4; ++t) {
      passA(x1p + (size_t)t * 64 * DHW);
      __syncthreads();
      passB();
      __syncthreads();
#pragma unroll
      for (int ks = 0; ks < 2; ++ks) {
        const int ko = ks * 32 + 8 * g;
        const int kg = t * 64 + ko;
        bf16x8 bh = *(const bf16x8*)&Xth[(16 * wv + l15) * XT_LD + ko];
        bf16x8 bl = *(const bf16x8*)&Xtl[(16 * wv + l15) * XT_LD + ko];
#pragma unroll
        for (int mt = 0; mt < 2; ++mt) {
          bf16x8 wh, wl;
          load_split8(Wq + (size_t)(mt * 16 + l15) * 256 + kg, wh, wl);
          qacc[mt] = MFMA16(wh, bh, qacc[mt]);
          qacc[mt] = MFMA16(wh, bl, qacc[mt]);
          qacc[mt] = MFMA16(wl, bh, qacc[mt]);
        }
      }
      __syncthreads();
    }
    const int x = 16 * wv + l15;
#pragma unroll
    for (int mt = 0; mt < 2; ++mt)
#pragma unroll
      for (int r = 0; r < 4; ++r) {
        short hh, ll;
        split_val(qacc[mt][r], hh, ll);
        Qh[x * QK_LD + mt * 16 + 4 * g + r] = (ushort_t)hh;
        Ql[x * QK_LD + mt * 16 + 4 * g + r] = (ushort_t)ll;
      }
  }

  f32x4 vacc[4][4];
  {
    f32x4 kacc[2];
#pragma unroll
    for (int mt = 0; mt < 2; ++mt) {
      int r0 = mt * 16 + 4 * g;
      kacc[mt] = (f32x4){bk[r0], bk[r0 + 1], bk[r0 + 2], bk[r0 + 3]};
    }
#pragma unroll
    for (int mt = 0; mt < 4; ++mt) {
      int r0 = 64 * wv + mt * 16 + 4 * g;
      f32x4 bb = (f32x4){bv[r0], bv[r0 + 1], bv[r0 + 2], bv[r0 + 3]};
#pragma unroll
      for (int nt = 0; nt < 4; ++nt) vacc[mt][nt] = bb;
    }
    const float* x2p = x2 + base;
    for (int t = 0; t < 4; ++t) {
      passA(x2p + (size_t)t * 64 * DHW);
      __syncthreads();
      passB();
      __syncthreads();
#pragma unroll
      for (int ks = 0; ks < 2; ++ks) {
        const int ko = ks * 32 + 8 * g;
        const int kg = t * 64 + ko;
        bf16x8 xh[4], xl[4];
#pragma unroll
        for (int nt = 0; nt < 4; ++nt) {
          xh[nt] = *(const bf16x8*)&Xth[(nt * 16 + l15) * XT_LD + ko];
          xl[nt] = *(const bf16x8*)&Xtl[(nt * 16 + l15) * XT_LD + ko];
        }
        {
          bf16x8 bh = *(const bf16x8*)&Xth[(16 * wv + l15) * XT_LD + ko];
          bf16x8 bl = *(const bf16x8*)&Xtl[(16 * wv + l15) * XT_LD + ko];
#pragma unroll
          for (int mt = 0; mt < 2; ++mt) {
            bf16x8 wh, wl;
            load_split8(Wk + (size_t)(mt * 16 + l15) * 256 + kg, wh, wl);
            kacc[mt] = MFMA16(wh, bh, kacc[mt]);
            kacc[mt] = MFMA16(wh, bl, kacc[mt]);
            kacc[mt] = MFMA16(wl, bh, kacc[mt]);
          }
        }
#pragma unroll
        for (int mt = 0; mt < 4; ++mt) {
          bf16x8 wh, wl;
          load_split8(Wv + (size_t)(64 * wv + mt * 16 + l15) * 256 + kg, wh, wl);
#pragma unroll
          for (int nt = 0; nt < 4; ++nt) {
            vacc[mt][nt] = MFMA16(wh, xh[nt], vacc[mt][nt]);
            vacc[mt][nt] = MFMA16(wh, xl[nt], vacc[mt][nt]);
            vacc[mt][nt] = MFMA16(wl, xh[nt], vacc[mt][nt]);
          }
        }
      }
      __syncthreads();
    }
    const int y = 16 * wv + l15;
#pragma unroll
    for (int mt = 0; mt < 2; ++mt)
#pragma unroll
      for (int r = 0; r < 4; ++r) {
        short hh, ll;
        split_val(kacc[mt][r], hh, ll);
        Kh[y * QK_LD + mt * 16 + 4 * g + r] = (ushort_t)hh;
        Kl[y * QK_LD + mt * 16 + 4 * g + r] = (ushort_t)ll;
      }
  }
  __syncthreads();

  {
    const int y = 16 * wv + l15;
    bf16x8 kh = *(const bf16x8*)&Kh[y * QK_LD + 8 * g];
    bf16x8 kl = *(const bf16x8*)&Kl[y * QK_LD + 8 * g];
    f32x4 acc[4];
#pragma unroll
    for (int mt = 0; mt < 4; ++mt) acc[mt] = (f32x4){0.f, 0.f, 0.f, 0.f};
#pragma unroll
    for (int mt = 0; mt < 4; ++mt) {
      bf16x8 qh = *(const bf16x8*)&Qh[(mt * 16 + l15) * QK_LD + 8 * g];
      bf16x8 ql = *(const bf16x8*)&Ql[(mt * 16 + l15) * QK_LD + 8 * g];
      acc[mt] = MFMA16(qh, kh, acc[mt]);
      acc[mt] = MFMA16(qh, kl, acc[mt]);
      acc[mt] = MFMA16(ql, kh, acc[mt]);
    }
#pragma unroll
    for (int mt = 0; mt < 4; ++mt)
#pragma unroll
      for (int r = 0; r < 4; ++r) {
        short hh, ll;
        split_val(acc[mt][r], hh, ll);
        Ah[(mt * 16 + 4 * g + r) * A_LD + y] = (ushort_t)hh;
        Al[(mt * 16 + 4 * g + r) * A_LD + y] = (ushort_t)ll;
      }
  }
  __syncthreads();

  {
    ushort_t* Vh = Vb + wv * 2304;
    ushort_t* Vl = Vh + 1152;
    const int cb = 64 * wv;
#pragma unroll
    for (int mt = 0; mt < 4; ++mt) {
#pragma unroll
      for (int nt = 0; nt < 4; ++nt)
#pragma unroll
        for (int r = 0; r < 4; ++r) {
          short hh, ll;
          split_val(vacc[mt][nt][r], hh, ll);
          Vh[(4 * g + r) * VB_LD + nt * 16 + l15] = (ushort_t)hh;
          Vl[(4 * g + r) * VB_LD + nt * 16 + l15] = (ushort_t)ll;
        }
      f32x4 oacc[4];
#pragma unroll
      for (int nt = 0; nt < 4; ++nt) oacc[nt] = (f32x4){0.f, 0.f, 0.f, 0.f};
#pragma unroll
      for (int ys = 0; ys < 2; ++ys) {
        const int yo = ys * 32 + 8 * g;
        bf16x8 vh8 = *(const bf16x8*)&Vh[l15 * VB_LD + yo];
        bf16x8 vl8 = *(const bf16x8*)&Vl[l15 * VB_LD + yo];
#pragma unroll
        for (int nt = 0; nt < 4; ++nt) {
          bf16x8 ah8 = *(const bf16x8*)&Ah[(nt * 16 + l15) * A_LD + yo];
          bf16x8 al8 = *(const bf16x8*)&Al[(nt * 16 + l15) * A_LD + yo];
          oacc[nt] = MFMA16(vh8, ah8, oacc[nt]);
          oacc[nt] = MFMA16(vh8, al8, oacc[nt]);
          oacc[nt] = MFMA16(vl8, ah8, oacc[nt]);
        }
      }
#pragma unroll
      for (int nt = 0; nt < 4; ++nt)
#pragma unroll
        for (int r = 0; r < 4; ++r)
          out[base + (size_t)(cb + mt * 16 + 4 * g + r) * DHW + nt * 16 + l15] = oacc[nt][r];
    }
  }
}

extern "C" void kernel_launch(void* const* d_in, const int* in_sizes, int n_in,
                              void* d_out, int out_size, void* d_ws, size_t ws_size,
                              hipStream_t stream)
{
  const float* x1 = (const float*)d_in[0];
  const float* x2 = (const float*)d_in[1];
  const float* Wq = (const float*)d_in[2];
  const float* bq = (const float*)d_in[3];
  const float* Wk = (const float*)d_in[4];
  const float* bk = (const float*)d_in[5];
  const float* Wv = (const float*)d_in[6];
  const float* bv = (const float*)d_in[7];
  float* out = (float*)d_out;

  if (d_ws && ws_size >= WS_FULL_BYTES) {
    ushort_t* ws = (ushort_t*)d_ws;
    hipLaunchKernelGGL(prep_w, dim3(320), dim3(256), 0, stream, Wq, Wk, Wv, ws);
    hipLaunchKernelGGL(qk_kernel, dim3(512), dim3(256), 0, stream, x1, x2, bq, bk, ws);
    hipLaunchKernelGGL(xattn_v3, dim3(4096), dim3(256), 0, stream, x2, bv, ws, out);
  } else {
    hipLaunchKernelGGL(xattn_fallback, dim3(NB * ND * NH), dim3(256), 0, stream,
                       x1, x2, Wq, bq, Wk, bk, Wv, bv, out);
  }
}